// Round 15
// baseline (235.734 us; speedup 1.0000x reference)
//
#include <hip/hip_runtime.h>
#include <hip/hip_bf16.h>
#include <stdint.h>

// Problem constants
#define B_   4
#define T_   512
#define P_   3584
#define S_   4096      // P_ + T_
#define H_   16
#define KH_  4
#define DM_  2048
#define DH_  128
#define NTOK 2048      // B_*T_
#define NCHUNK 3
#define NROWS 32768    // B_*H_*T_ q-rows

typedef __attribute__((ext_vector_type(8)))  short          bf16x8;
typedef __attribute__((ext_vector_type(4)))  float          f32x4;
typedef __attribute__((ext_vector_type(16))) float          f32x16;
typedef __attribute__((ext_vector_type(4)))  float          f4v;
typedef __attribute__((ext_vector_type(4)))  unsigned short us4v;

__device__ __forceinline__ unsigned short f2bf(float x) {
    union { float f; unsigned u; } v; v.f = x;
    unsigned r = v.u + 0x7FFFu + ((v.u >> 16) & 1u);   // RNE
    return (unsigned short)(r >> 16);
}
__device__ __forceinline__ float bf2f(unsigned short b) {
    union { unsigned u; float f; } v; v.u = ((unsigned)b) << 16; return v.f;
}
// packed f32x2 -> bf16x2 (compiler emits v_cvt_pk_bf16_f32)
__device__ __forceinline__ unsigned pkbf(float a, float b) {
    __hip_bfloat162 h = __float22bfloat162_rn(float2{a, b});
    union { __hip_bfloat162 h; unsigned u; } cv; cv.h = h; return cv.u;
}
// raw v_exp_f32: r = 2^x
__device__ __forceinline__ float ex2(float x) {
    float r; asm("v_exp_f32 %0, %1" : "=v"(r) : "v"(x)); return r;
}
__device__ __forceinline__ float max3f(float a, float b, float c) {
    float r; asm("v_max3_f32 %0, %1, %2, %3" : "=v"(r) : "v"(a), "v"(b), "v"(c)); return r;
}
// HW sin/cos, input in revolutions (pre-reduced to [0,1))
__device__ __forceinline__ float sin_rev(float xf) {
    float r; asm("v_sin_f32 %0, %1" : "=v"(r) : "v"(xf)); return r;
}
__device__ __forceinline__ float cos_rev(float xf) {
    float r; asm("v_cos_f32 %0, %1" : "=v"(r) : "v"(xf)); return r;
}

// async global->LDS, 16B per lane; LDS dest is wave-uniform base + lane*16
#define GLDS16(gp, lp) __builtin_amdgcn_global_load_lds( \
    (const __attribute__((address_space(1))) void*)(gp), \
    (__attribute__((address_space(3))) void*)(lp), 16, 0, 0)

// ---------------------------------------------------------------------------
// 1) fp32 -> bf16 conversions (x, w_q|w_k|w_v concat, w_o, k cache restrided)
//    + v_cache transpose into vT [B,KH,DH,S] (blocks >= 2048).
// ---------------------------------------------------------------------------
__global__ __launch_bounds__(256) void convert_all(
    const float* __restrict__ x,  const float* __restrict__ wq,
    const float* __restrict__ wk, const float* __restrict__ wv,
    const float* __restrict__ wo, const float* __restrict__ kc,
    const float* __restrict__ vc,
    unsigned short* __restrict__ xb,   unsigned short* __restrict__ wqkvb,
    unsigned short* __restrict__ wob,  unsigned short* __restrict__ kfull,
    unsigned short* __restrict__ vT)
{
    __shared__ unsigned short tile[64][65];
    if (blockIdx.x >= 2048) {
        // ---- v_cache [B,KH,P,DH] fp32 -> vT [B,KH,DH,S] bf16, 64x64 tiles
        const int id = blockIdx.x - 2048;      // 0..1791
        const int bk = id / 112;               // b*KH+kh
        const int rem = id % 112;
        const int st = rem >> 1;               // s-tile 0..55
        const int dt = rem & 1;                // d-tile 0..1
        const float* src = vc + ((size_t)bk * P_ + st * 64) * DH_ + dt * 64;
        const int tq = threadIdx.x & 15;       // d-quad
        const int ts = threadIdx.x >> 4;       // s row
        #pragma unroll
        for (int i = 0; i < 4; ++i) {
            const int si = ts + i * 16;
            f4v v = *(const f4v*)(src + (size_t)si * DH_ + tq * 4);
            tile[si][tq*4+0] = f2bf(v[0]); tile[si][tq*4+1] = f2bf(v[1]);
            tile[si][tq*4+2] = f2bf(v[2]); tile[si][tq*4+3] = f2bf(v[3]);
        }
        __syncthreads();
        unsigned short* dst = vT + ((size_t)bk * DH_ + dt * 64) * S_ + st * 64;
        const int sq = threadIdx.x & 15;       // s-quad
        const int td = threadIdx.x >> 4;       // d row
        #pragma unroll
        for (int i = 0; i < 4; ++i) {
            const int di = td + i * 16;
            us4v o;
            o[0] = tile[sq*4+0][di]; o[1] = tile[sq*4+1][di];
            o[2] = tile[sq*4+2][di]; o[3] = tile[sq*4+3][di];
            *(us4v*)(dst + (size_t)di * S_ + sq * 4) = o;
        }
        return;
    }
    const long total = 5505024;  // total vec4 tasks
    for (long i = (long)blockIdx.x * 256 + threadIdx.x; i < total;
         i += 2048L * 256) {
        const f4v* src; us4v* dst; long s4, d4;
        if (i < 1048576)      { src=(const f4v*)x;  dst=(us4v*)xb;              s4=i;         d4=s4; }
        else if (i < 2097152) { src=(const f4v*)wq; dst=(us4v*)wqkvb;           s4=i-1048576; d4=s4; }
        else if (i < 2359296) { src=(const f4v*)wk; dst=(us4v*)(wqkvb+4194304); s4=i-2097152; d4=s4; }
        else if (i < 2621440) { src=(const f4v*)wv; dst=(us4v*)(wqkvb+5242880); s4=i-2359296; d4=s4; }
        else if (i < 3670016) { src=(const f4v*)wo; dst=(us4v*)wob;             s4=i-2621440; d4=s4; }
        else                  { s4=i-3670016; long bk=s4/114688;                // P_*DH_/4
                                d4=bk*131072+(s4-bk*114688);                     // S_*DH_/4
                                src=(const f4v*)kc; dst=(us4v*)kfull; }
        f4v v = src[s4];
        us4v o; o[0]=f2bf(v[0]); o[1]=f2bf(v[1]); o[2]=f2bf(v[2]); o[3]=f2bf(v[3]);
        dst[d4] = o;
    }
}

// ---------------------------------------------------------------------------
// 2) bf16 GEMM, C[M][N] = A[M][K] * B[N][K]^T  (m97 structure, 128x128 tile)
//    XCD-aware block decode (requires nbn % 8 == 0).
//    nks in {1,2}: K-slice ks writes partial to C + ks*M*N (contiguous).
// ---------------------------------------------------------------------------
__global__ __launch_bounds__(256) void gemm_bt(
    const unsigned short* __restrict__ A, const unsigned short* __restrict__ Bw,
    void* __restrict__ C, int M, int N, int K, int obf16, int nks)
{
    __shared__ short As[2][128 * 32];
    __shared__ short Bs[2][128 * 32];
    const int tid = threadIdx.x, lane = tid & 63, w = tid >> 6;
    int bid = blockIdx.x;
    const int bps = gridDim.x / nks;                 // blocks per K-slice
    const int ks = bid / bps;
    bid -= ks * bps;
    const int Ksl = K / nks;
    const int k0base = ks * Ksl;
    const int nbn = N >> 7;
    const int cpx = nbn >> 3;                        // B-columns per XCD
    const int xcd = bid & 7;
    const int rr = bid >> 3;
    const int bm = rr / cpx, bn = xcd * cpx + rr % cpx;
    const int m0 = bm << 7, n0 = bn << 7;
    const int wm = w >> 1, wn = w & 1;

    f32x4 acc[4][4];
    #pragma unroll
    for (int i = 0; i < 4; ++i)
        #pragma unroll
        for (int j = 0; j < 4; ++j)
            #pragma unroll
            for (int r = 0; r < 4; ++r) acc[i][j][r] = 0.f;

    const int arow = lane >> 2;
    const int acol = (lane & 3) << 3;

    auto stage = [&](int buf, int k0) {
        #pragma unroll
        for (int cc = 0; cc < 2; ++cc) {
            const int c = 2 * w + cc;
            GLDS16(A  + (size_t)(m0 + c * 16 + arow) * K + k0 + acol, &As[buf][c * 512]);
            GLDS16(Bw + (size_t)(n0 + c * 16 + arow) * K + k0 + acol, &Bs[buf][c * 512]);
        }
    };

    stage(0, k0base);
    __syncthreads();

    const int nk = Ksl >> 5;
    const int fr = lane & 15, fk = (lane >> 4) << 3;
    for (int t = 0; t < nk; ++t) {
        const int buf = t & 1;
        if (t + 1 < nk) stage(buf ^ 1, k0base + ((t + 1) << 5));
        bf16x8 a[4], b[4];
        #pragma unroll
        for (int i = 0; i < 4; ++i)
            a[i] = *(const bf16x8*)&As[buf][(wm * 64 + i * 16 + fr) * 32 + fk];
        #pragma unroll
        for (int j = 0; j < 4; ++j)
            b[j] = *(const bf16x8*)&Bs[buf][(wn * 64 + j * 16 + fr) * 32 + fk];
        __builtin_amdgcn_s_setprio(1);
        #pragma unroll
        for (int i = 0; i < 4; ++i)
            #pragma unroll
            for (int j = 0; j < 4; ++j)
                acc[i][j] = __builtin_amdgcn_mfma_f32_16x16x32_bf16(a[i], b[j], acc[i][j], 0, 0, 0);
        __builtin_amdgcn_s_setprio(0);
        __syncthreads();
    }

    const int er = lane >> 4, ec = lane & 15;
    const size_t cbase = (size_t)ks * M * N;
    #pragma unroll
    for (int i = 0; i < 4; ++i)
        #pragma unroll
        for (int j = 0; j < 4; ++j)
            #pragma unroll
            for (int r = 0; r < 4; ++r) {
                const int row = m0 + wm * 64 + i * 16 + er * 4 + r;
                const int col = n0 + wn * 64 + j * 16 + ec;
                if (obf16) ((unsigned short*)C)[cbase + (size_t)row * N + col] = f2bf(acc[i][j][r]);
                else       ((float*)C)[cbase + (size_t)row * N + col] = acc[i][j][r];
            }
}

// ---------------------------------------------------------------------------
// 2b) fp32 split-K reduce: out = p0 + p1 (vectorized, grid-stride)
// ---------------------------------------------------------------------------
__global__ __launch_bounds__(256) void reduce2(
    const float* __restrict__ p0, const float* __restrict__ p1,
    float* __restrict__ out)
{
    const int total4 = (DM_ * NTOK) / 4;   // 1,048,576 vec4
    for (int i = blockIdx.x * 256 + threadIdx.x; i < total4; i += 1024 * 256) {
        f4v a = ((const f4v*)p0)[i];
        f4v b = ((const f4v*)p1)[i];
        a[0] += b[0]; a[1] += b[1]; a[2] += b[2]; a[3] += b[3];
        ((f4v*)out)[i] = a;
    }
}

// ---------------------------------------------------------------------------
// 3) per-head RMSNorm + RoPE from TWO bf16 qkv split-K partials (summed on
//    load); writes bf16 Q (pre-scaled by log2(e)/sqrt(DH)), K rows into
//    kfull, V rows transposed into vT. 4 waves/block, one task per wave.
// ---------------------------------------------------------------------------
__global__ __launch_bounds__(256) void norm_rope(
    const unsigned short* __restrict__ qkv0, const unsigned short* __restrict__ qkv1,
    const float* __restrict__ qw, const float* __restrict__ kw,
    const int* __restrict__ pos,
    unsigned short* __restrict__ Qb, unsigned short* __restrict__ Kf,
    unsigned short* __restrict__ VT)
{
    const int task = blockIdx.x * 4 + (threadIdx.x >> 6);
    const int n = task / 24, idx = task % 24;
    const int lane = threadIdx.x & 63;
    const int b = n >> 9, t = n & 511;

    if (idx >= 20) {                          // V heads: sum partials + transpose
        const int kh = idx - 20;
        const size_t off = (size_t)n * 3072 + 2560 + kh * 128;
        const unsigned short* s0_ = qkv0 + off;
        const unsigned short* s1_ = qkv1 + off;
        unsigned short* dstT = VT + (size_t)(b * KH_ + kh) * DH_ * S_ + (P_ + t);
        dstT[(size_t)lane * S_]        = f2bf(bf2f(s0_[lane]) + bf2f(s1_[lane]));
        dstT[(size_t)(lane + 64) * S_] = f2bf(bf2f(s0_[lane + 64]) + bf2f(s1_[lane + 64]));
        return;
    }
    const bool isq = idx < 16;
    const int hh = isq ? idx : (idx - 16);
    const size_t off = (size_t)n * 3072 + (isq ? hh * 128 : 2048 + hh * 128);
    const unsigned short* s0_ = qkv0 + off;
    const unsigned short* s1_ = qkv1 + off;
    const float* wn_ = isq ? qw : kw;
    float x0 = bf2f(s0_[lane]) + bf2f(s1_[lane]);
    float x1 = bf2f(s0_[lane + 64]) + bf2f(s1_[lane + 64]);
    float ss = x0 * x0 + x1 * x1;
    #pragma unroll
    for (int m = 1; m < 64; m <<= 1) ss += __shfl_xor(ss, m);
    const float rinv = rsqrtf(ss * (1.0f / 128.0f) + 1e-6f);
    float y0 = x0 * rinv * wn_[lane];
    float y1 = x1 * rinv * wn_[lane + 64];
    // inv_freq = 2^(-lane*log2(1e6)/64)
    const float fr = ex2(-(float)lane * (19.931568569324174f / 64.0f));
    const float th = (float)pos[n] * fr;
    const float xr = th * 0.15915494309189535f;    // revolutions
    const float xf = xr - floorf(xr);
    const float sn = sin_rev(xf), cs = cos_rev(xf);
    float o0 = cs * y0 - sn * y1;
    float o1 = cs * y1 + sn * y0;
    unsigned short* dst;
    if (isq) {
        // log2(e) / sqrt(128): softmax runs in exp2 domain
        const float qs = 0.08838834764831845f * 1.4426950408889634f;
        o0 *= qs; o1 *= qs;
        dst = Qb + ((size_t)(b * H_ + hh) * T_ + t) * DH_;
    } else {
        dst = Kf + ((size_t)(b * KH_ + hh) * S_ + P_ + t) * DH_;
    }
    dst[lane]      = f2bf(o0);
    dst[lane + 64] = f2bf(o1);
}

// ---------------------------------------------------------------------------
// 4) GQA flash attention, 3-way split-KV (stride-3 tile interleave),
//    XCD-aware block swizzle, 4-deep LDS ring, CROSS-TILE PIPELINE:
//    QK^T(j+1) MFMAs issue before softmax(j) VALU so the matrix pipe fills
//    the VALU window; st result consumed one iteration after issue.
//    One barrier + one counted vmcnt per iteration (FIFO: 2 tiles in flight).
// ---------------------------------------------------------------------------
__global__ __launch_bounds__(256, 2) void attn(
    const unsigned short* __restrict__ Qb, const unsigned short* __restrict__ Kf,
    const unsigned short* __restrict__ VT, unsigned short* __restrict__ op0,
    unsigned short* __restrict__ op1, unsigned short* __restrict__ op2,
    float2* __restrict__ ml)
{
    __shared__ short Ks[4][32 * 128];   // [s][d], 16B-chunk XOR(row&15) swizzle
    __shared__ short Vs[4][128 * 32];   // [d][s], 16B-chunk XOR((row>>1)&3) swizzle

    const int tid = threadIdx.x, lane = tid & 63, w = tid >> 6;
    // XCD-aware decode: 16 blocks sharing one (b,kvh) K/V panel land on one XCD
    const int c = blockIdx.x >> 8;                  // KV chunk 0..2
    const int y = blockIdx.x & 255;
    const int xcd = y & 7, slot = y >> 3;
    const int p = xcd + 8 * (slot >> 4);            // panel = b*KH + kvh, 0..15
    const int inner = slot & 15;
    const int b = p >> 2, kvh = p & 3;
    const int h = kvh * 4 + (inner >> 2);
    const int qt = inner & 3;
    const int t0 = qt * 128;

    const unsigned short* Qrow = Qb + (size_t)(b * H_ + h) * T_ * DH_;
    const unsigned short* Kb   = Kf + (size_t)(b * KH_ + kvh) * S_ * DH_;
    const unsigned short* VTb  = VT + (size_t)(b * KH_ + kvh) * DH_ * S_;

    const int ql = lane & 31;
    const int hi = lane >> 5;

    bf16x8 qf[8];
    {
        const unsigned short* qp = Qrow + (size_t)(t0 + w * 32 + ql) * DH_ + hi * 8;
        #pragma unroll
        for (int d0 = 0; d0 < 8; ++d0) qf[d0] = *(const bf16x8*)(qp + d0 * 16);
    }

    f32x16 o[4];
    #pragma unroll
    for (int d = 0; d < 4; ++d)
        #pragma unroll
        for (int r = 0; r < 16; ++r) o[d][r] = 0.f;
    float m_run = -INFINITY, l_run = 0.f;

    const int q_pos = P_ + t0 + w * 32 + ql;
    const int s_end_wave = P_ + t0 + w * 32 + 32;
    const int nt_full = (P_ + t0 + 128) >> 5;       // 116,120,124,128 for qt=0..3
    // chunk c handles tiles c, c+3, c+6, ... (stride-3 interleave, balanced)
    const int nj = (nt_full - c + 2) / 3;

    auto stage = [&](int buf, int tile) {
        const int s0 = tile << 5;
        #pragma unroll
        for (int cc = 0; cc < 2; ++cc) {
            const int cx = 2 * w + cc;
            const int krow = cx * 4 + (lane >> 4);
            const int kel  = 8 * ((lane & 15) ^ (krow & 15));
            GLDS16(Kb + (size_t)(s0 + krow) * DH_ + kel, &Ks[buf][cx * 512]);
            const int vrow = cx * 16 + (lane >> 2);
            const int vel  = 8 * ((lane & 3) ^ ((lane >> 3) & 3));  // (vrow>>1)&3
            GLDS16(VTb + (size_t)vrow * S_ + s0 + vel, &Vs[buf][cx * 512]);
        }
    };

    // QK^T (swapped): stv[r] = S^T[s=(r&3)+8*(r>>2)+4*hi][q=ql] (log2 domain)
    auto qk = [&](int tile, int buf, f32x16& stv) {
        #pragma unroll
        for (int r = 0; r < 16; ++r) stv[r] = 0.f;
        if ((tile << 5) < s_end_wave) {
            const char* kbase = (const char*)&Ks[buf][0] + ql * 256;
            const int sw = 16 * (ql & 15);
            #pragma unroll
            for (int d0 = 0; d0 < 8; ++d0) {
                bf16x8 kfr = *(const bf16x8*)(kbase + ((d0 * 32 + 16 * hi) ^ sw));
                stv = __builtin_amdgcn_mfma_f32_32x32x16_bf16(kfr, qf[d0], stv, 0, 0, 0);
            }
        }
    };

    // prologue: 2 tiles in flight (4 GLDS per wave each)
    stage(0, c);
    if (nj > 1) {
        stage(1, c + 3);
        asm volatile("s_waitcnt vmcnt(4)" ::: "memory");   // tile 0 done, tile 1 in flight
    } else {
        asm volatile("s_waitcnt vmcnt(0)" ::: "memory");
    }
    __builtin_amdgcn_s_barrier();
    f32x16 st;
    qk(c, 0, st);

    for (int j = 0; j < nj; ++j) {
        if (j + 2 < nj) stage((j + 2) & 3, c + 3 * (j + 2));
        f32x16 st2;
        if (j + 1 < nj) {
            // outstanding: t(j+1) [4] + (t(j+2) [4] if staged). Complete t(j+1).
            if (j + 2 < nj) asm volatile("s_waitcnt vmcnt(4)" ::: "memory");
            else            asm volatile("s_waitcnt vmcnt(0)" ::: "memory");
            __builtin_amdgcn_s_barrier();
            qk(c + 3 * (j + 1), (j + 1) & 3, st2);   // MFMAs issue; result used NEXT iter
        }
        const int t = c + 3 * j;
        const int s0 = t << 5;
        const int buf = j & 3;
        if (s0 < s_end_wave) {
            // ---- causal mask (near-diagonal only)
            if (s0 + 31 > P_ + t0 + w * 32) {
                #pragma unroll
                for (int r = 0; r < 16; ++r) {
                    const int srow = (r & 3) + 8 * (r >> 2) + 4 * hi;
                    if (s0 + srow > q_pos) st[r] = -INFINITY;
                }
            }
            // ---- online softmax in exp2 domain, defer-max (THR = 8*log2e ~ 11.5)
            float m0_ = max3f(st[0], st[1], st[2]),  m1_ = max3f(st[3], st[4], st[5]);
            float m2_ = max3f(st[6], st[7], st[8]),  m3_ = max3f(st[9], st[10], st[11]);
            float m4_ = max3f(st[12], st[13], st[14]);
            float pmax = fmaxf(max3f(m0_, m1_, m2_), max3f(m3_, m4_, st[15]));
            pmax = fmaxf(pmax, __shfl_xor(pmax, 32));
            if (!__all(pmax <= m_run + 11.5f)) {
                const float m_new = fmaxf(m_run, pmax);
                const float alpha = ex2(m_run - m_new);
                l_run *= alpha;
                #pragma unroll
                for (int r = 0; r < 16; ++r) {
                    const int qr = (r & 3) + 8 * (r >> 2) + 4 * hi;
                    const float a = __shfl(alpha, qr);
                    #pragma unroll
                    for (int d = 0; d < 4; ++d) o[d][r] *= a;
                }
                m_run = m_new;
            }
            // ---- exp in place (st becomes P), running sum
            float psum = 0.f;
            #pragma unroll
            for (int r = 0; r < 16; ++r) { st[r] = ex2(st[r] - m_run); psum += st[r]; }
            psum += __shfl_xor(psum, 32);
            l_run += psum;
            // ---- P -> bf16 A-fragments (cvt_pk + transient partner exchange)
            unsigned pk[8];
            #pragma unroll
            for (int u = 0; u < 8; ++u) pk[u] = pkbf(st[2 * u], st[2 * u + 1]);
            union { bf16x8 v; unsigned u[4]; } pa0, pa1;
            { unsigned xx = (unsigned)__shfl_xor((int)pk[2], 32); pa0.u[0] = hi ? xx : pk[0]; }
            { unsigned xx = (unsigned)__shfl_xor((int)pk[3], 32); pa0.u[1] = hi ? xx : pk[1]; }
            { unsigned xx = (unsigned)__shfl_xor((int)pk[0], 32); pa0.u[2] = hi ? pk[2] : xx; }
            { unsigned xx = (unsigned)__shfl_xor((int)pk[1], 32); pa0.u[3] = hi ? pk[3] : xx; }
            { unsigned xx = (unsigned)__shfl_xor((int)pk[6], 32); pa1.u[0] = hi ? xx : pk[4]; }
            { unsigned xx = (unsigned)__shfl_xor((int)pk[7], 32); pa1.u[1] = hi ? xx : pk[5]; }
            { unsigned xx = (unsigned)__shfl_xor((int)pk[4], 32); pa1.u[2] = hi ? pk[6] : xx; }
            { unsigned xx = (unsigned)__shfl_xor((int)pk[5], 32); pa1.u[3] = hi ? pk[7] : xx; }
            // ---- PV: B-operand from vT LDS tile
            #pragma unroll
            for (int ch = 0; ch < 2; ++ch)
                #pragma unroll
                for (int db = 0; db < 4; ++db) {
                    const int vrow = db * 32 + ql;
                    bf16x8 vf = *(const bf16x8*)&Vs[buf][vrow * 32 + 8 * ((2 * ch + hi) ^ ((ql >> 1) & 3))];
                    o[db] = __builtin_amdgcn_mfma_f32_32x32x16_bf16(
                        ch ? pa1.v : pa0.v, vf, o[db], 0, 0, 0);
                }
        }
        st = st2;
    }

    // ---- epilogue: write unnormalized partial O (bf16) + (m,l)
    unsigned short* op = (c == 0) ? op0 : (c == 1) ? op1 : op2;
    const int rowbase = (b * H_ + h) * T_ + t0 + w * 32;
    if (hi == 0) ml[c * NROWS + rowbase + ql] = float2{m_run, l_run};
    #pragma unroll
    for (int r = 0; r < 16; ++r) {
        const int qr = (r & 3) + 8 * (r >> 2) + 4 * hi;
        unsigned short* orow = op + (size_t)(rowbase + qr) * DH_;
        #pragma unroll
        for (int d = 0; d < 4; ++d)
            orow[d * 32 + ql] = f2bf(o[d][r]);
    }
}

// ---------------------------------------------------------------------------
// 5) combine partials: out = (sum_c 2^{m_c-m*} O_c) / (sum_c 2^{m_c-m*} l_c)
// ---------------------------------------------------------------------------
__global__ __launch_bounds__(256) void combine(
    const float2* __restrict__ ml,
    const unsigned short* __restrict__ op0, const unsigned short* __restrict__ op1,
    const unsigned short* __restrict__ op2, unsigned short* __restrict__ ao)
{
    const int row = blockIdx.x * 4 + (threadIdx.x >> 6);
    const int lane = threadIdx.x & 63;
    const float2 a0 = ml[row], a1 = ml[NROWS + row], a2 = ml[2 * NROWS + row];
    const float m = fmaxf(a0.x, fmaxf(a1.x, a2.x));
    const float w0 = ex2(a0.x - m), w1 = ex2(a1.x - m), w2 = ex2(a2.x - m);
    const float Linv = 1.0f / (w0 * a0.y + w1 * a1.y + w2 * a2.y);
    const size_t src = (size_t)row * DH_ + 2 * lane;
    const unsigned u0 = *(const unsigned*)(op0 + src);
    const unsigned u1 = *(const unsigned*)(op1 + src);
    const unsigned u2 = *(const unsigned*)(op2 + src);
    const float v0 = (bf2f((unsigned short)u0) * w0 + bf2f((unsigned short)u1) * w1 +
                      bf2f((unsigned short)u2) * w2) * Linv;
    const float v1 = (bf2f((unsigned short)(u0 >> 16)) * w0 + bf2f((unsigned short)(u1 >> 16)) * w1 +
                      bf2f((unsigned short)(u2 >> 16)) * w2) * Linv;
    // row = (b*H+h)*T + t  ->  ao[(b*T+t)][h*DH + d]
    const int t = row & 511, h = (row >> 9) & 15, b = row >> 13;
    unsigned short* dst = ao + ((size_t)(b * T_ + t) * (H_ * DH_)) + h * DH_ + 2 * lane;
    *(unsigned*)dst = pkbf(v0, v1);
}

// ---------------------------------------------------------------------------
// launch
// ---------------------------------------------------------------------------
extern "C" void kernel_launch(void* const* d_in, const int* in_sizes, int n_in,
                              void* d_out, int out_size, void* d_ws, size_t ws_size,
                              hipStream_t stream)
{
    const float* x   = (const float*)d_in[0];
    const float* kc  = (const float*)d_in[1];
    const float* vc  = (const float*)d_in[2];
    const float* wq  = (const float*)d_in[3];
    const float* wk  = (const float*)d_in[4];
    const float* wv  = (const float*)d_in[5];
    const float* wo  = (const float*)d_in[6];
    const float* qnw = (const float*)d_in[7];
    const float* knw = (const float*)d_in[8];
    const int*   pos = (const int*)d_in[9];
    float* out = (float*)d_out;

    char* ws = (char*)d_ws;
    // Live P1->P3:
    unsigned short* xb    = (unsigned short*)(ws + 0);          //  8 MB   x bf16
    unsigned short* wqkvb = (unsigned short*)(ws + 8388608);    // 12 MB   w_qkv bf16
    unsigned short* wob   = (unsigned short*)(ws + 20971520);   //  8 MB   w_o bf16 (P1-P6)
    unsigned short* qkvp0 = (unsigned short*)(ws + 29360128);   // 12.6 MB qkv partial 0
    unsigned short* qkvp1 = (unsigned short*)(ws + 41943040);   // 12.6 MB qkv partial 1 (contiguous)
    unsigned short* qb    = (unsigned short*)(ws + 54525952);   //  8 MB   Q bf16 (P3-P4)
    unsigned short* kfull = (unsigned short*)(ws + 62914560);   // 16 MB   K bf16 (P1-P4)
    unsigned short* vT    = (unsigned short*)(ws + 79691776);   // 16 MB   V bf16 (P1-P4)  -> ends 96468992
    // Overlays (regions dead by the time they're reused):
    unsigned short* op0   = (unsigned short*)(ws + 0);          //  8 MB  (xb region, P4-P5)
    unsigned short* op1   = (unsigned short*)(ws + 8388608);    //  8 MB  (wqkvb region, P4-P5)
    float2*         ml    = (float2*)(ws + 16777216);           //  1 MB  (wqkvb region, P4-P5)
    unsigned short* op2   = (unsigned short*)(ws + 29360128);   //  8 MB  (qkvp0 region, P4-P5)
    unsigned short* ao    = (unsigned short*)(ws + 37748736);   //  8 MB  (qkvp1 region, P5-P6)
    float*          po0   = (float*)(ws + 62914560);            // 16.8MB (kfull region, P6-P7)
    // po1 = po0 + M*N implicitly at ws+79691776 (vT region) — contiguous split-K partials

    hipLaunchKernelGGL(convert_all, dim3(2048 + 1792), dim3(256), 0, stream,
                       x, wq, wk, wv, wo, kc, vc, xb, wqkvb, wob, kfull, vT);
    hipLaunchKernelGGL(gemm_bt, dim3(2 * 16 * 24), dim3(256), 0, stream,
                       xb, wqkvb, (void*)qkvp0, 2048, 3072, 2048, 1, 2);
    hipLaunchKernelGGL(norm_rope, dim3(NTOK * 24 / 4), dim3(256), 0, stream,
                       qkvp0, qkvp1, qnw, knw, pos, qb, kfull, vT);
    hipLaunchKernelGGL(attn, dim3(NCHUNK * 256), dim3(256), 0, stream,
                       qb, kfull, vT, op0, op1, op2, ml);
    hipLaunchKernelGGL(combine, dim3(NROWS / 4), dim3(256), 0, stream,
                       ml, op0, op1, op2, ao);
    hipLaunchKernelGGL(gemm_bt, dim3(2 * 16 * 16), dim3(256), 0, stream,
                       ao, wob, (void*)po0, 2048, 2048, 2048, 0, 2);
    hipLaunchKernelGGL(reduce2, dim3(1024), dim3(256), 0, stream,
                       po0, po0 + (size_t)DM_ * NTOK, out);
}

// Round 16
// 217.051 us; speedup vs baseline: 1.0861x; 1.0861x over previous
//
#include <hip/hip_runtime.h>
#include <hip/hip_bf16.h>
#include <stdint.h>

// Problem constants
#define B_   4
#define T_   512
#define P_   3584
#define S_   4096      // P_ + T_
#define H_   16
#define KH_  4
#define DM_  2048
#define DH_  128
#define NTOK 2048      // B_*T_
#define NCHUNK 3
#define NTC  43        // unused (stride interleave), kept for reference
#define NROWS 32768    // B_*H_*T_ q-rows

typedef __attribute__((ext_vector_type(8)))  short          bf16x8;
typedef __attribute__((ext_vector_type(4)))  float          f32x4;
typedef __attribute__((ext_vector_type(16))) float          f32x16;
typedef __attribute__((ext_vector_type(4)))  float          f4v;
typedef __attribute__((ext_vector_type(4)))  unsigned short us4v;

__device__ __forceinline__ unsigned short f2bf(float x) {
    union { float f; unsigned u; } v; v.f = x;
    unsigned r = v.u + 0x7FFFu + ((v.u >> 16) & 1u);   // RNE
    return (unsigned short)(r >> 16);
}
__device__ __forceinline__ float bf2f(unsigned short b) {
    union { unsigned u; float f; } v; v.u = ((unsigned)b) << 16; return v.f;
}
// packed f32x2 -> bf16x2 (compiler emits v_cvt_pk_bf16_f32)
__device__ __forceinline__ unsigned pkbf(float a, float b) {
    __hip_bfloat162 h = __float22bfloat162_rn(float2{a, b});
    union { __hip_bfloat162 h; unsigned u; } cv; cv.h = h; return cv.u;
}
// raw v_exp_f32: r = 2^x
__device__ __forceinline__ float ex2(float x) {
    float r; asm("v_exp_f32 %0, %1" : "=v"(r) : "v"(x)); return r;
}
__device__ __forceinline__ float max3f(float a, float b, float c) {
    float r; asm("v_max3_f32 %0, %1, %2, %3" : "=v"(r) : "v"(a), "v"(b), "v"(c)); return r;
}
// HW sin/cos, input in revolutions (pre-reduced to [0,1))
__device__ __forceinline__ float sin_rev(float xf) {
    float r; asm("v_sin_f32 %0, %1" : "=v"(r) : "v"(xf)); return r;
}
__device__ __forceinline__ float cos_rev(float xf) {
    float r; asm("v_cos_f32 %0, %1" : "=v"(r) : "v"(xf)); return r;
}

// async global->LDS, 16B per lane; LDS dest is wave-uniform base + lane*16
#define GLDS16(gp, lp) __builtin_amdgcn_global_load_lds( \
    (const __attribute__((address_space(1))) void*)(gp), \
    (__attribute__((address_space(3))) void*)(lp), 16, 0, 0)

// ---------------------------------------------------------------------------
// 1) fp32 -> bf16 conversions (x, w_q|w_k|w_v concat, w_o, k cache restrided)
//    + v_cache transpose into vT [B,KH,DH,S] (blocks >= 2048).
// ---------------------------------------------------------------------------
__global__ __launch_bounds__(256) void convert_all(
    const float* __restrict__ x,  const float* __restrict__ wq,
    const float* __restrict__ wk, const float* __restrict__ wv,
    const float* __restrict__ wo, const float* __restrict__ kc,
    const float* __restrict__ vc,
    unsigned short* __restrict__ xb,   unsigned short* __restrict__ wqkvb,
    unsigned short* __restrict__ wob,  unsigned short* __restrict__ kfull,
    unsigned short* __restrict__ vT)
{
    __shared__ unsigned short tile[64][65];
    if (blockIdx.x >= 2048) {
        // ---- v_cache [B,KH,P,DH] fp32 -> vT [B,KH,DH,S] bf16, 64x64 tiles
        const int id = blockIdx.x - 2048;      // 0..1791
        const int bk = id / 112;               // b*KH+kh
        const int rem = id % 112;
        const int st = rem >> 1;               // s-tile 0..55
        const int dt = rem & 1;                // d-tile 0..1
        const float* src = vc + ((size_t)bk * P_ + st * 64) * DH_ + dt * 64;
        const int tq = threadIdx.x & 15;       // d-quad
        const int ts = threadIdx.x >> 4;       // s row
        #pragma unroll
        for (int i = 0; i < 4; ++i) {
            const int si = ts + i * 16;
            f4v v = *(const f4v*)(src + (size_t)si * DH_ + tq * 4);
            tile[si][tq*4+0] = f2bf(v[0]); tile[si][tq*4+1] = f2bf(v[1]);
            tile[si][tq*4+2] = f2bf(v[2]); tile[si][tq*4+3] = f2bf(v[3]);
        }
        __syncthreads();
        unsigned short* dst = vT + ((size_t)bk * DH_ + dt * 64) * S_ + st * 64;
        const int sq = threadIdx.x & 15;       // s-quad
        const int td = threadIdx.x >> 4;       // d row
        #pragma unroll
        for (int i = 0; i < 4; ++i) {
            const int di = td + i * 16;
            us4v o;
            o[0] = tile[sq*4+0][di]; o[1] = tile[sq*4+1][di];
            o[2] = tile[sq*4+2][di]; o[3] = tile[sq*4+3][di];
            *(us4v*)(dst + (size_t)di * S_ + sq * 4) = o;
        }
        return;
    }
    const long total = 5505024;  // total vec4 tasks
    for (long i = (long)blockIdx.x * 256 + threadIdx.x; i < total;
         i += 2048L * 256) {
        const f4v* src; us4v* dst; long s4, d4;
        if (i < 1048576)      { src=(const f4v*)x;  dst=(us4v*)xb;              s4=i;         d4=s4; }
        else if (i < 2097152) { src=(const f4v*)wq; dst=(us4v*)wqkvb;           s4=i-1048576; d4=s4; }
        else if (i < 2359296) { src=(const f4v*)wk; dst=(us4v*)(wqkvb+4194304); s4=i-2097152; d4=s4; }
        else if (i < 2621440) { src=(const f4v*)wv; dst=(us4v*)(wqkvb+5242880); s4=i-2359296; d4=s4; }
        else if (i < 3670016) { src=(const f4v*)wo; dst=(us4v*)wob;             s4=i-2621440; d4=s4; }
        else                  { s4=i-3670016; long bk=s4/114688;                // P_*DH_/4
                                d4=bk*131072+(s4-bk*114688);                     // S_*DH_/4
                                src=(const f4v*)kc; dst=(us4v*)kfull; }
        f4v v = src[s4];
        us4v o; o[0]=f2bf(v[0]); o[1]=f2bf(v[1]); o[2]=f2bf(v[2]); o[3]=f2bf(v[3]);
        dst[d4] = o;
    }
}

// ---------------------------------------------------------------------------
// 2) bf16 GEMM, C[M][N] = A[M][K] * B[N][K]^T  (m97 structure, 128x128 tile)
//    XCD-aware block decode (requires nbn % 8 == 0).
//    nks in {1,2}: K-slice ks writes partial to C + ks*M*N (contiguous).
// ---------------------------------------------------------------------------
__global__ __launch_bounds__(256) void gemm_bt(
    const unsigned short* __restrict__ A, const unsigned short* __restrict__ Bw,
    void* __restrict__ C, int M, int N, int K, int obf16, int nks)
{
    __shared__ short As[2][128 * 32];
    __shared__ short Bs[2][128 * 32];
    const int tid = threadIdx.x, lane = tid & 63, w = tid >> 6;
    int bid = blockIdx.x;
    const int bps = gridDim.x / nks;                 // blocks per K-slice
    const int ks = bid / bps;
    bid -= ks * bps;
    const int Ksl = K / nks;
    const int k0base = ks * Ksl;
    const int nbn = N >> 7;
    const int cpx = nbn >> 3;                        // B-columns per XCD
    const int xcd = bid & 7;
    const int rr = bid >> 3;
    const int bm = rr / cpx, bn = xcd * cpx + rr % cpx;
    const int m0 = bm << 7, n0 = bn << 7;
    const int wm = w >> 1, wn = w & 1;

    f32x4 acc[4][4];
    #pragma unroll
    for (int i = 0; i < 4; ++i)
        #pragma unroll
        for (int j = 0; j < 4; ++j)
            #pragma unroll
            for (int r = 0; r < 4; ++r) acc[i][j][r] = 0.f;

    const int arow = lane >> 2;
    const int acol = (lane & 3) << 3;

    auto stage = [&](int buf, int k0) {
        #pragma unroll
        for (int cc = 0; cc < 2; ++cc) {
            const int c = 2 * w + cc;
            GLDS16(A  + (size_t)(m0 + c * 16 + arow) * K + k0 + acol, &As[buf][c * 512]);
            GLDS16(Bw + (size_t)(n0 + c * 16 + arow) * K + k0 + acol, &Bs[buf][c * 512]);
        }
    };

    stage(0, k0base);
    __syncthreads();

    const int nk = Ksl >> 5;
    const int fr = lane & 15, fk = (lane >> 4) << 3;
    for (int t = 0; t < nk; ++t) {
        const int buf = t & 1;
        if (t + 1 < nk) stage(buf ^ 1, k0base + ((t + 1) << 5));
        bf16x8 a[4], b[4];
        #pragma unroll
        for (int i = 0; i < 4; ++i)
            a[i] = *(const bf16x8*)&As[buf][(wm * 64 + i * 16 + fr) * 32 + fk];
        #pragma unroll
        for (int j = 0; j < 4; ++j)
            b[j] = *(const bf16x8*)&Bs[buf][(wn * 64 + j * 16 + fr) * 32 + fk];
        __builtin_amdgcn_s_setprio(1);
        #pragma unroll
        for (int i = 0; i < 4; ++i)
            #pragma unroll
            for (int j = 0; j < 4; ++j)
                acc[i][j] = __builtin_amdgcn_mfma_f32_16x16x32_bf16(a[i], b[j], acc[i][j], 0, 0, 0);
        __builtin_amdgcn_s_setprio(0);
        __syncthreads();
    }

    const int er = lane >> 4, ec = lane & 15;
    const size_t cbase = (size_t)ks * M * N;
    #pragma unroll
    for (int i = 0; i < 4; ++i)
        #pragma unroll
        for (int j = 0; j < 4; ++j)
            #pragma unroll
            for (int r = 0; r < 4; ++r) {
                const int row = m0 + wm * 64 + i * 16 + er * 4 + r;
                const int col = n0 + wn * 64 + j * 16 + ec;
                if (obf16) ((unsigned short*)C)[cbase + (size_t)row * N + col] = f2bf(acc[i][j][r]);
                else       ((float*)C)[cbase + (size_t)row * N + col] = acc[i][j][r];
            }
}

// ---------------------------------------------------------------------------
// 2b) fp32 split-K reduce: out = p0 + p1 (vectorized, grid-stride)
// ---------------------------------------------------------------------------
__global__ __launch_bounds__(256) void reduce2(
    const float* __restrict__ p0, const float* __restrict__ p1,
    float* __restrict__ out)
{
    const int total4 = (DM_ * NTOK) / 4;   // 1,048,576 vec4
    for (int i = blockIdx.x * 256 + threadIdx.x; i < total4; i += 1024 * 256) {
        f4v a = ((const f4v*)p0)[i];
        f4v b = ((const f4v*)p1)[i];
        a[0] += b[0]; a[1] += b[1]; a[2] += b[2]; a[3] += b[3];
        ((f4v*)out)[i] = a;
    }
}

// ---------------------------------------------------------------------------
// 3) per-head RMSNorm + RoPE from TWO bf16 qkv split-K partials (summed on
//    load); writes bf16 Q (pre-scaled by log2(e)/sqrt(DH)), K rows into
//    kfull, V rows transposed into vT. 4 waves/block, one task per wave.
// ---------------------------------------------------------------------------
__global__ __launch_bounds__(256) void norm_rope(
    const unsigned short* __restrict__ qkv0, const unsigned short* __restrict__ qkv1,
    const float* __restrict__ qw, const float* __restrict__ kw,
    const int* __restrict__ pos,
    unsigned short* __restrict__ Qb, unsigned short* __restrict__ Kf,
    unsigned short* __restrict__ VT)
{
    const int task = blockIdx.x * 4 + (threadIdx.x >> 6);
    const int n = task / 24, idx = task % 24;
    const int lane = threadIdx.x & 63;
    const int b = n >> 9, t = n & 511;

    if (idx >= 20) {                          // V heads: sum partials + transpose
        const int kh = idx - 20;
        const size_t off = (size_t)n * 3072 + 2560 + kh * 128;
        const unsigned short* s0_ = qkv0 + off;
        const unsigned short* s1_ = qkv1 + off;
        unsigned short* dstT = VT + (size_t)(b * KH_ + kh) * DH_ * S_ + (P_ + t);
        dstT[(size_t)lane * S_]        = f2bf(bf2f(s0_[lane]) + bf2f(s1_[lane]));
        dstT[(size_t)(lane + 64) * S_] = f2bf(bf2f(s0_[lane + 64]) + bf2f(s1_[lane + 64]));
        return;
    }
    const bool isq = idx < 16;
    const int hh = isq ? idx : (idx - 16);
    const size_t off = (size_t)n * 3072 + (isq ? hh * 128 : 2048 + hh * 128);
    const unsigned short* s0_ = qkv0 + off;
    const unsigned short* s1_ = qkv1 + off;
    const float* wn_ = isq ? qw : kw;
    float x0 = bf2f(s0_[lane]) + bf2f(s1_[lane]);
    float x1 = bf2f(s0_[lane + 64]) + bf2f(s1_[lane + 64]);
    float ss = x0 * x0 + x1 * x1;
    #pragma unroll
    for (int m = 1; m < 64; m <<= 1) ss += __shfl_xor(ss, m);
    const float rinv = rsqrtf(ss * (1.0f / 128.0f) + 1e-6f);
    float y0 = x0 * rinv * wn_[lane];
    float y1 = x1 * rinv * wn_[lane + 64];
    // inv_freq = 2^(-lane*log2(1e6)/64)
    const float fr = ex2(-(float)lane * (19.931568569324174f / 64.0f));
    const float th = (float)pos[n] * fr;
    const float xr = th * 0.15915494309189535f;    // revolutions
    const float xf = xr - floorf(xr);
    const float sn = sin_rev(xf), cs = cos_rev(xf);
    float o0 = cs * y0 - sn * y1;
    float o1 = cs * y1 + sn * y0;
    unsigned short* dst;
    if (isq) {
        // log2(e) / sqrt(128): softmax runs in exp2 domain
        const float qs = 0.08838834764831845f * 1.4426950408889634f;
        o0 *= qs; o1 *= qs;
        dst = Qb + ((size_t)(b * H_ + hh) * T_ + t) * DH_;
    } else {
        dst = Kf + ((size_t)(b * KH_ + hh) * S_ + P_ + t) * DH_;
    }
    dst[lane]      = f2bf(o0);
    dst[lane + 64] = f2bf(o1);
}

// ---------------------------------------------------------------------------
// 4) GQA flash attention, 3-way split-KV (stride-3 tile interleave),
//    XCD-aware block swizzle, 3-deep LDS ring with counted vmcnt + raw
//    s_barrier. exp2-domain online softmax, in-place exp, transient
//    shfl_xor P-exchange.  (r13 body — measured best, 94.1-94.8 us)
// ---------------------------------------------------------------------------
__global__ __launch_bounds__(256, 3) void attn(
    const unsigned short* __restrict__ Qb, const unsigned short* __restrict__ Kf,
    const unsigned short* __restrict__ VT, unsigned short* __restrict__ op0,
    unsigned short* __restrict__ op1, unsigned short* __restrict__ op2,
    float2* __restrict__ ml)
{
    __shared__ short Ks[3][32 * 128];   // [s][d], 16B-chunk XOR(row&15) swizzle
    __shared__ short Vs[3][128 * 32];   // [d][s], 16B-chunk XOR((row>>1)&3) swizzle

    const int tid = threadIdx.x, lane = tid & 63, w = tid >> 6;
    // XCD-aware decode: 16 blocks sharing one (b,kvh) K/V panel land on one XCD
    const int c = blockIdx.x >> 8;                  // KV chunk 0..2
    const int y = blockIdx.x & 255;
    const int xcd = y & 7, slot = y >> 3;
    const int p = xcd + 8 * (slot >> 4);            // panel = b*KH + kvh, 0..15
    const int inner = slot & 15;
    const int b = p >> 2, kvh = p & 3;
    const int h = kvh * 4 + (inner >> 2);
    const int qt = inner & 3;
    const int t0 = qt * 128;

    const unsigned short* Qrow = Qb + (size_t)(b * H_ + h) * T_ * DH_;
    const unsigned short* Kb   = Kf + (size_t)(b * KH_ + kvh) * S_ * DH_;
    const unsigned short* VTb  = VT + (size_t)(b * KH_ + kvh) * DH_ * S_;

    const int ql = lane & 31;
    const int hi = lane >> 5;

    bf16x8 qf[8];
    {
        const unsigned short* qp = Qrow + (size_t)(t0 + w * 32 + ql) * DH_ + hi * 8;
        #pragma unroll
        for (int d0 = 0; d0 < 8; ++d0) qf[d0] = *(const bf16x8*)(qp + d0 * 16);
    }

    f32x16 o[4];
    #pragma unroll
    for (int d = 0; d < 4; ++d)
        #pragma unroll
        for (int r = 0; r < 16; ++r) o[d][r] = 0.f;
    float m_run = -INFINITY, l_run = 0.f;

    const int q_pos = P_ + t0 + w * 32 + ql;
    const int s_end_wave = P_ + t0 + w * 32 + 32;
    const int nt_full = (P_ + t0 + 128) >> 5;       // 116,120,124,128 for qt=0..3
    // chunk c handles tiles c, c+3, c+6, ... (stride-3 interleave, balanced)
    const int nj = (nt_full - c + 2) / 3;

    auto stage = [&](int buf, int tile) {
        const int s0 = tile << 5;
        #pragma unroll
        for (int cc = 0; cc < 2; ++cc) {
            const int cx = 2 * w + cc;
            const int krow = cx * 4 + (lane >> 4);
            const int kel  = 8 * ((lane & 15) ^ (krow & 15));
            GLDS16(Kb + (size_t)(s0 + krow) * DH_ + kel, &Ks[buf][cx * 512]);
            const int vrow = cx * 16 + (lane >> 2);
            const int vel  = 8 * ((lane & 3) ^ ((lane >> 3) & 3));  // (vrow>>1)&3
            GLDS16(VTb + (size_t)vrow * S_ + s0 + vel, &Vs[buf][cx * 512]);
        }
    };

    // prologue: 2 tiles in flight (4 GLDS per wave each)
    stage(0, c);
    if (nj > 1) stage(1, c + 3);

    for (int j = 0; j < nj; ++j) {
        // counted vmcnt: oldest 4 loads (= this tile) done; next tile's 4 stay in flight
        if (j + 1 < nj) asm volatile("s_waitcnt vmcnt(4)" ::: "memory");
        else            asm volatile("s_waitcnt vmcnt(0)" ::: "memory");
        __builtin_amdgcn_s_barrier();
        if (j + 2 < nj) stage((j + 2) % 3, c + 3 * (j + 2));

        const int t = c + 3 * j;
        const int s0 = t << 5;
        const int buf = j % 3;
        if (s0 < s_end_wave) {
            // ---- QK^T (swapped): st[r] = S^T[s=(r&3)+8*(r>>2)+4*hi][q=ql] (log2 domain)
            f32x16 st;
            #pragma unroll
            for (int r = 0; r < 16; ++r) st[r] = 0.f;
            {
                const char* kbase = (const char*)&Ks[buf][0] + ql * 256;
                const int sw = 16 * (ql & 15);
                #pragma unroll
                for (int d0 = 0; d0 < 8; ++d0) {
                    bf16x8 kfr = *(const bf16x8*)(kbase + ((d0 * 32 + 16 * hi) ^ sw));
                    st = __builtin_amdgcn_mfma_f32_32x32x16_bf16(kfr, qf[d0], st, 0, 0, 0);
                }
            }
            if (s0 + 31 > P_ + t0 + w * 32) {
                #pragma unroll
                for (int r = 0; r < 16; ++r) {
                    const int srow = (r & 3) + 8 * (r >> 2) + 4 * hi;
                    if (s0 + srow > q_pos) st[r] = -INFINITY;
                }
            }
            // ---- online softmax in exp2 domain, defer-max (THR = 8*log2e ~ 11.5)
            float m0_ = max3f(st[0], st[1], st[2]),  m1_ = max3f(st[3], st[4], st[5]);
            float m2_ = max3f(st[6], st[7], st[8]),  m3_ = max3f(st[9], st[10], st[11]);
            float m4_ = max3f(st[12], st[13], st[14]);
            float pmax = fmaxf(max3f(m0_, m1_, m2_), max3f(m3_, m4_, st[15]));
            pmax = fmaxf(pmax, __shfl_xor(pmax, 32));
            if (!__all(pmax <= m_run + 11.5f)) {
                const float m_new = fmaxf(m_run, pmax);
                const float alpha = ex2(m_run - m_new);
                l_run *= alpha;
                #pragma unroll
                for (int r = 0; r < 16; ++r) {
                    const int qr = (r & 3) + 8 * (r >> 2) + 4 * hi;
                    const float a = __shfl(alpha, qr);
                    #pragma unroll
                    for (int d = 0; d < 4; ++d) o[d][r] *= a;
                }
                m_run = m_new;
            }
            // ---- exp in place (st becomes P), running sum
            float psum = 0.f;
            #pragma unroll
            for (int r = 0; r < 16; ++r) { st[r] = ex2(st[r] - m_run); psum += st[r]; }
            psum += __shfl_xor(psum, 32);
            l_run += psum;
            // ---- P -> bf16 A-fragments (cvt_pk + transient partner exchange)
            unsigned pk[8];
            #pragma unroll
            for (int u = 0; u < 8; ++u) pk[u] = pkbf(st[2 * u], st[2 * u + 1]);
            union { bf16x8 v; unsigned u[4]; } pa0, pa1;
            { unsigned xx = (unsigned)__shfl_xor((int)pk[2], 32); pa0.u[0] = hi ? xx : pk[0]; }
            { unsigned xx = (unsigned)__shfl_xor((int)pk[3], 32); pa0.u[1] = hi ? xx : pk[1]; }
            { unsigned xx = (unsigned)__shfl_xor((int)pk[0], 32); pa0.u[2] = hi ? pk[2] : xx; }
            { unsigned xx = (unsigned)__shfl_xor((int)pk[1], 32); pa0.u[3] = hi ? pk[3] : xx; }
            { unsigned xx = (unsigned)__shfl_xor((int)pk[6], 32); pa1.u[0] = hi ? xx : pk[4]; }
            { unsigned xx = (unsigned)__shfl_xor((int)pk[7], 32); pa1.u[1] = hi ? xx : pk[5]; }
            { unsigned xx = (unsigned)__shfl_xor((int)pk[4], 32); pa1.u[2] = hi ? pk[6] : xx; }
            { unsigned xx = (unsigned)__shfl_xor((int)pk[5], 32); pa1.u[3] = hi ? pk[7] : xx; }
            // ---- PV: B-operand from vT LDS tile
            #pragma unroll
            for (int ch = 0; ch < 2; ++ch)
                #pragma unroll
                for (int db = 0; db < 4; ++db) {
                    const int vrow = db * 32 + ql;
                    bf16x8 vf = *(const bf16x8*)&Vs[buf][vrow * 32 + 8 * ((2 * ch + hi) ^ ((ql >> 1) & 3))];
                    o[db] = __builtin_amdgcn_mfma_f32_32x32x16_bf16(
                        ch ? pa1.v : pa0.v, vf, o[db], 0, 0, 0);
                }
        }
    }

    // ---- epilogue: write unnormalized partial O (bf16) + (m,l)
    unsigned short* op = (c == 0) ? op0 : (c == 1) ? op1 : op2;
    const int rowbase = (b * H_ + h) * T_ + t0 + w * 32;
    if (hi == 0) ml[c * NROWS + rowbase + ql] = float2{m_run, l_run};
    #pragma unroll
    for (int r = 0; r < 16; ++r) {
        const int qr = (r & 3) + 8 * (r >> 2) + 4 * hi;
        unsigned short* orow = op + (size_t)(rowbase + qr) * DH_;
        #pragma unroll
        for (int d = 0; d < 4; ++d)
            orow[d * 32 + ql] = f2bf(o[d][r]);
    }
}

// ---------------------------------------------------------------------------
// 5) combine partials: out = (sum_c 2^{m_c-m*} O_c) / (sum_c 2^{m_c-m*} l_c)
// ---------------------------------------------------------------------------
__global__ __launch_bounds__(256) void combine(
    const float2* __restrict__ ml,
    const unsigned short* __restrict__ op0, const unsigned short* __restrict__ op1,
    const unsigned short* __restrict__ op2, unsigned short* __restrict__ ao)
{
    const int row = blockIdx.x * 4 + (threadIdx.x >> 6);
    const int lane = threadIdx.x & 63;
    const float2 a0 = ml[row], a1 = ml[NROWS + row], a2 = ml[2 * NROWS + row];
    const float m = fmaxf(a0.x, fmaxf(a1.x, a2.x));
    const float w0 = ex2(a0.x - m), w1 = ex2(a1.x - m), w2 = ex2(a2.x - m);
    const float Linv = 1.0f / (w0 * a0.y + w1 * a1.y + w2 * a2.y);
    const size_t src = (size_t)row * DH_ + 2 * lane;
    const unsigned u0 = *(const unsigned*)(op0 + src);
    const unsigned u1 = *(const unsigned*)(op1 + src);
    const unsigned u2 = *(const unsigned*)(op2 + src);
    const float v0 = (bf2f((unsigned short)u0) * w0 + bf2f((unsigned short)u1) * w1 +
                      bf2f((unsigned short)u2) * w2) * Linv;
    const float v1 = (bf2f((unsigned short)(u0 >> 16)) * w0 + bf2f((unsigned short)(u1 >> 16)) * w1 +
                      bf2f((unsigned short)(u2 >> 16)) * w2) * Linv;
    // row = (b*H+h)*T + t  ->  ao[(b*T+t)][h*DH + d]
    const int t = row & 511, h = (row >> 9) & 15, b = row >> 13;
    unsigned short* dst = ao + ((size_t)(b * T_ + t) * (H_ * DH_)) + h * DH_ + 2 * lane;
    *(unsigned*)dst = pkbf(v0, v1);
}

// ---------------------------------------------------------------------------
// launch
// ---------------------------------------------------------------------------
extern "C" void kernel_launch(void* const* d_in, const int* in_sizes, int n_in,
                              void* d_out, int out_size, void* d_ws, size_t ws_size,
                              hipStream_t stream)
{
    const float* x   = (const float*)d_in[0];
    const float* kc  = (const float*)d_in[1];
    const float* vc  = (const float*)d_in[2];
    const float* wq  = (const float*)d_in[3];
    const float* wk  = (const float*)d_in[4];
    const float* wv  = (const float*)d_in[5];
    const float* wo  = (const float*)d_in[6];
    const float* qnw = (const float*)d_in[7];
    const float* knw = (const float*)d_in[8];
    const int*   pos = (const int*)d_in[9];
    float* out = (float*)d_out;

    char* ws = (char*)d_ws;
    // Live P1->P3:
    unsigned short* xb    = (unsigned short*)(ws + 0);          //  8 MB   x bf16
    unsigned short* wqkvb = (unsigned short*)(ws + 8388608);    // 12 MB   w_qkv bf16
    unsigned short* wob   = (unsigned short*)(ws + 20971520);   //  8 MB   w_o bf16 (P1-P6)
    unsigned short* qkvp0 = (unsigned short*)(ws + 29360128);   // 12.6 MB qkv partial 0
    unsigned short* qkvp1 = (unsigned short*)(ws + 41943040);   // 12.6 MB qkv partial 1 (contiguous)
    unsigned short* qb    = (unsigned short*)(ws + 54525952);   //  8 MB   Q bf16 (P3-P4)
    unsigned short* kfull = (unsigned short*)(ws + 62914560);   // 16 MB   K bf16 (P1-P4)
    unsigned short* vT    = (unsigned short*)(ws + 79691776);   // 16 MB   V bf16 (P1-P4)  -> ends 96468992
    // Overlays (regions dead by the time they're reused):
    unsigned short* op0   = (unsigned short*)(ws + 0);          //  8 MB  (xb region, P4-P5)
    unsigned short* op1   = (unsigned short*)(ws + 8388608);    //  8 MB  (wqkvb region, P4-P5)
    float2*         ml    = (float2*)(ws + 16777216);           //  1 MB  (wqkvb region, P4-P5)
    unsigned short* op2   = (unsigned short*)(ws + 29360128);   //  8 MB  (qkvp0 region, P4-P5)
    unsigned short* ao    = (unsigned short*)(ws + 37748736);   //  8 MB  (qkvp1 region, P5-P6)
    float*          po0   = (float*)(ws + 62914560);            // 16.8MB (kfull region, P6-P7)
    // po1 = po0 + M*N implicitly at ws+79691776 (vT region) — contiguous split-K partials

    hipLaunchKernelGGL(convert_all, dim3(2048 + 1792), dim3(256), 0, stream,
                       x, wq, wk, wv, wo, kc, vc, xb, wqkvb, wob, kfull, vT);
    hipLaunchKernelGGL(gemm_bt, dim3(2 * 16 * 24), dim3(256), 0, stream,
                       xb, wqkvb, (void*)qkvp0, 2048, 3072, 2048, 1, 2);
    hipLaunchKernelGGL(norm_rope, dim3(NTOK * 24 / 4), dim3(256), 0, stream,
                       qkvp0, qkvp1, qnw, knw, pos, qb, kfull, vT);
    hipLaunchKernelGGL(attn, dim3(NCHUNK * 256), dim3(256), 0, stream,
                       qb, kfull, vT, op0, op1, op2, ml);
    hipLaunchKernelGGL(combine, dim3(NROWS / 4), dim3(256), 0, stream,
                       ml, op0, op1, op2, ao);
    hipLaunchKernelGGL(gemm_bt, dim3(2 * 16 * 16), dim3(256), 0, stream,
                       ao, wob, (void*)po0, 2048, 2048, 2048, 0, 2);
    hipLaunchKernelGGL(reduce2, dim3(1024), dim3(256), 0, stream,
                       po0, po0 + (size_t)DM_ * NTOK, out);
}

// Round 17
// 213.850 us; speedup vs baseline: 1.1023x; 1.0150x over previous
//
#include <hip/hip_runtime.h>
#include <hip/hip_bf16.h>
#include <stdint.h>

// Problem constants
#define B_   4
#define T_   512
#define P_   3584
#define S_   4096      // P_ + T_
#define H_   16
#define KH_  4
#define DM_  2048
#define DH_  128
#define NTOK 2048      // B_*T_
#define NCHUNK 3
#define NROWS 32768    // B_*H_*T_ q-rows

typedef __attribute__((ext_vector_type(8)))  short          bf16x8;
typedef __attribute__((ext_vector_type(4)))  float          f32x4;
typedef __attribute__((ext_vector_type(16))) float          f32x16;
typedef __attribute__((ext_vector_type(4)))  float          f4v;
typedef __attribute__((ext_vector_type(4)))  unsigned short us4v;

__device__ __forceinline__ unsigned short f2bf(float x) {
    union { float f; unsigned u; } v; v.f = x;
    unsigned r = v.u + 0x7FFFu + ((v.u >> 16) & 1u);   // RNE
    return (unsigned short)(r >> 16);
}
__device__ __forceinline__ float bf2f(unsigned short b) {
    union { unsigned u; float f; } v; v.u = ((unsigned)b) << 16; return v.f;
}
// packed f32x2 -> bf16x2 (compiler emits v_cvt_pk_bf16_f32)
__device__ __forceinline__ unsigned pkbf(float a, float b) {
    __hip_bfloat162 h = __float22bfloat162_rn(float2{a, b});
    union { __hip_bfloat162 h; unsigned u; } cv; cv.h = h; return cv.u;
}
// raw v_exp_f32: r = 2^x
__device__ __forceinline__ float ex2(float x) {
    float r; asm("v_exp_f32 %0, %1" : "=v"(r) : "v"(x)); return r;
}
__device__ __forceinline__ float max3f(float a, float b, float c) {
    float r; asm("v_max3_f32 %0, %1, %2, %3" : "=v"(r) : "v"(a), "v"(b), "v"(c)); return r;
}
// HW sin/cos, input in revolutions (pre-reduced to [0,1))
__device__ __forceinline__ float sin_rev(float xf) {
    float r; asm("v_sin_f32 %0, %1" : "=v"(r) : "v"(xf)); return r;
}
__device__ __forceinline__ float cos_rev(float xf) {
    float r; asm("v_cos_f32 %0, %1" : "=v"(r) : "v"(xf)); return r;
}

// async global->LDS, 16B per lane; LDS dest is wave-uniform base + lane*16
#define GLDS16(gp, lp) __builtin_amdgcn_global_load_lds( \
    (const __attribute__((address_space(1))) void*)(gp), \
    (__attribute__((address_space(3))) void*)(lp), 16, 0, 0)

// ---------------------------------------------------------------------------
// 1) fp32 -> bf16 conversions (x, w_q|w_k|w_v concat, w_o, k cache restrided)
//    + v_cache transpose into vT [B,KH,DH,S] (blocks >= 2048).
// ---------------------------------------------------------------------------
__global__ __launch_bounds__(256) void convert_all(
    const float* __restrict__ x,  const float* __restrict__ wq,
    const float* __restrict__ wk, const float* __restrict__ wv,
    const float* __restrict__ wo, const float* __restrict__ kc,
    const float* __restrict__ vc,
    unsigned short* __restrict__ xb,   unsigned short* __restrict__ wqkvb,
    unsigned short* __restrict__ wob,  unsigned short* __restrict__ kfull,
    unsigned short* __restrict__ vT)
{
    __shared__ unsigned short tile[64][65];
    if (blockIdx.x >= 2048) {
        // ---- v_cache [B,KH,P,DH] fp32 -> vT [B,KH,DH,S] bf16, 64x64 tiles
        const int id = blockIdx.x - 2048;      // 0..1791
        const int bk = id / 112;               // b*KH+kh
        const int rem = id % 112;
        const int st = rem >> 1;               // s-tile 0..55
        const int dt = rem & 1;                // d-tile 0..1
        const float* src = vc + ((size_t)bk * P_ + st * 64) * DH_ + dt * 64;
        const int tq = threadIdx.x & 15;       // d-quad
        const int ts = threadIdx.x >> 4;       // s row
        #pragma unroll
        for (int i = 0; i < 4; ++i) {
            const int si = ts + i * 16;
            f4v v = *(const f4v*)(src + (size_t)si * DH_ + tq * 4);
            tile[si][tq*4+0] = f2bf(v[0]); tile[si][tq*4+1] = f2bf(v[1]);
            tile[si][tq*4+2] = f2bf(v[2]); tile[si][tq*4+3] = f2bf(v[3]);
        }
        __syncthreads();
        unsigned short* dst = vT + ((size_t)bk * DH_ + dt * 64) * S_ + st * 64;
        const int sq = threadIdx.x & 15;       // s-quad
        const int td = threadIdx.x >> 4;       // d row
        #pragma unroll
        for (int i = 0; i < 4; ++i) {
            const int di = td + i * 16;
            us4v o;
            o[0] = tile[sq*4+0][di]; o[1] = tile[sq*4+1][di];
            o[2] = tile[sq*4+2][di]; o[3] = tile[sq*4+3][di];
            *(us4v*)(dst + (size_t)di * S_ + sq * 4) = o;
        }
        return;
    }
    const long total = 5505024;  // total vec4 tasks
    for (long i = (long)blockIdx.x * 256 + threadIdx.x; i < total;
         i += 2048L * 256) {
        const f4v* src; us4v* dst; long s4, d4;
        if (i < 1048576)      { src=(const f4v*)x;  dst=(us4v*)xb;              s4=i;         d4=s4; }
        else if (i < 2097152) { src=(const f4v*)wq; dst=(us4v*)wqkvb;           s4=i-1048576; d4=s4; }
        else if (i < 2359296) { src=(const f4v*)wk; dst=(us4v*)(wqkvb+4194304); s4=i-2097152; d4=s4; }
        else if (i < 2621440) { src=(const f4v*)wv; dst=(us4v*)(wqkvb+5242880); s4=i-2359296; d4=s4; }
        else if (i < 3670016) { src=(const f4v*)wo; dst=(us4v*)wob;             s4=i-2621440; d4=s4; }
        else                  { s4=i-3670016; long bk=s4/114688;                // P_*DH_/4
                                d4=bk*131072+(s4-bk*114688);                     // S_*DH_/4
                                src=(const f4v*)kc; dst=(us4v*)kfull; }
        f4v v = src[s4];
        us4v o; o[0]=f2bf(v[0]); o[1]=f2bf(v[1]); o[2]=f2bf(v[2]); o[3]=f2bf(v[3]);
        dst[d4] = o;
    }
}

// ---------------------------------------------------------------------------
// 2) bf16 GEMM, C[M][N] = A[M][K] * B[N][K]^T  (m97 structure, 128x128 tile)
//    XCD-aware block decode (requires nbn % 8 == 0).
//    nks in {1,2}: K-slice ks writes partial to C + ks*M*N (contiguous).
// ---------------------------------------------------------------------------
__global__ __launch_bounds__(256) void gemm_bt(
    const unsigned short* __restrict__ A, const unsigned short* __restrict__ Bw,
    void* __restrict__ C, int M, int N, int K, int obf16, int nks)
{
    __shared__ short As[2][128 * 32];
    __shared__ short Bs[2][128 * 32];
    const int tid = threadIdx.x, lane = tid & 63, w = tid >> 6;
    int bid = blockIdx.x;
    const int bps = gridDim.x / nks;                 // blocks per K-slice
    const int ks = bid / bps;
    bid -= ks * bps;
    const int Ksl = K / nks;
    const int k0base = ks * Ksl;
    const int nbn = N >> 7;
    const int cpx = nbn >> 3;                        // B-columns per XCD
    const int xcd = bid & 7;
    const int rr = bid >> 3;
    const int bm = rr / cpx, bn = xcd * cpx + rr % cpx;
    const int m0 = bm << 7, n0 = bn << 7;
    const int wm = w >> 1, wn = w & 1;

    f32x4 acc[4][4];
    #pragma unroll
    for (int i = 0; i < 4; ++i)
        #pragma unroll
        for (int j = 0; j < 4; ++j)
            #pragma unroll
            for (int r = 0; r < 4; ++r) acc[i][j][r] = 0.f;

    const int arow = lane >> 2;
    const int acol = (lane & 3) << 3;

    auto stage = [&](int buf, int k0) {
        #pragma unroll
        for (int cc = 0; cc < 2; ++cc) {
            const int c = 2 * w + cc;
            GLDS16(A  + (size_t)(m0 + c * 16 + arow) * K + k0 + acol, &As[buf][c * 512]);
            GLDS16(Bw + (size_t)(n0 + c * 16 + arow) * K + k0 + acol, &Bs[buf][c * 512]);
        }
    };

    stage(0, k0base);
    __syncthreads();

    const int nk = Ksl >> 5;
    const int fr = lane & 15, fk = (lane >> 4) << 3;
    for (int t = 0; t < nk; ++t) {
        const int buf = t & 1;
        if (t + 1 < nk) stage(buf ^ 1, k0base + ((t + 1) << 5));
        bf16x8 a[4], b[4];
        #pragma unroll
        for (int i = 0; i < 4; ++i)
            a[i] = *(const bf16x8*)&As[buf][(wm * 64 + i * 16 + fr) * 32 + fk];
        #pragma unroll
        for (int j = 0; j < 4; ++j)
            b[j] = *(const bf16x8*)&Bs[buf][(wn * 64 + j * 16 + fr) * 32 + fk];
        __builtin_amdgcn_s_setprio(1);
        #pragma unroll
        for (int i = 0; i < 4; ++i)
            #pragma unroll
            for (int j = 0; j < 4; ++j)
                acc[i][j] = __builtin_amdgcn_mfma_f32_16x16x32_bf16(a[i], b[j], acc[i][j], 0, 0, 0);
        __builtin_amdgcn_s_setprio(0);
        __syncthreads();
    }

    const int er = lane >> 4, ec = lane & 15;
    const size_t cbase = (size_t)ks * M * N;
    #pragma unroll
    for (int i = 0; i < 4; ++i)
        #pragma unroll
        for (int j = 0; j < 4; ++j)
            #pragma unroll
            for (int r = 0; r < 4; ++r) {
                const int row = m0 + wm * 64 + i * 16 + er * 4 + r;
                const int col = n0 + wn * 64 + j * 16 + ec;
                if (obf16) ((unsigned short*)C)[cbase + (size_t)row * N + col] = f2bf(acc[i][j][r]);
                else       ((float*)C)[cbase + (size_t)row * N + col] = acc[i][j][r];
            }
}

// ---------------------------------------------------------------------------
// 2b) fp32 split-K reduce: out = p0 + p1 (vectorized, grid-stride)
// ---------------------------------------------------------------------------
__global__ __launch_bounds__(256) void reduce2(
    const float* __restrict__ p0, const float* __restrict__ p1,
    float* __restrict__ out)
{
    const int total4 = (DM_ * NTOK) / 4;   // 1,048,576 vec4
    for (int i = blockIdx.x * 256 + threadIdx.x; i < total4; i += 1024 * 256) {
        f4v a = ((const f4v*)p0)[i];
        f4v b = ((const f4v*)p1)[i];
        a[0] += b[0]; a[1] += b[1]; a[2] += b[2]; a[3] += b[3];
        ((f4v*)out)[i] = a;
    }
}

// ---------------------------------------------------------------------------
// 3) per-head RMSNorm + RoPE from TWO bf16 qkv split-K partials (summed on
//    load); writes bf16 Q (pre-scaled by log2(e)/sqrt(DH)) and K rows into
//    kfull. V heads handled by vnew_transpose. 20 tasks/token, 4 waves/block.
// ---------------------------------------------------------------------------
__global__ __launch_bounds__(256) void norm_rope(
    const unsigned short* __restrict__ qkv0, const unsigned short* __restrict__ qkv1,
    const float* __restrict__ qw, const float* __restrict__ kw,
    const int* __restrict__ pos,
    unsigned short* __restrict__ Qb, unsigned short* __restrict__ Kf)
{
    const int task = blockIdx.x * 4 + (threadIdx.x >> 6);
    const int n = task / 20, idx = task % 20;
    const int lane = threadIdx.x & 63;
    const int b = n >> 9, t = n & 511;

    const bool isq = idx < 16;
    const int hh = isq ? idx : (idx - 16);
    const size_t off = (size_t)n * 3072 + (isq ? hh * 128 : 2048 + hh * 128);
    const unsigned short* s0_ = qkv0 + off;
    const unsigned short* s1_ = qkv1 + off;
    const float* wn_ = isq ? qw : kw;
    float x0 = bf2f(s0_[lane]) + bf2f(s1_[lane]);
    float x1 = bf2f(s0_[lane + 64]) + bf2f(s1_[lane + 64]);
    float ss = x0 * x0 + x1 * x1;
    #pragma unroll
    for (int m = 1; m < 64; m <<= 1) ss += __shfl_xor(ss, m);
    const float rinv = rsqrtf(ss * (1.0f / 128.0f) + 1e-6f);
    float y0 = x0 * rinv * wn_[lane];
    float y1 = x1 * rinv * wn_[lane + 64];
    // inv_freq = 2^(-lane*log2(1e6)/64)
    const float fr = ex2(-(float)lane * (19.931568569324174f / 64.0f));
    const float th = (float)pos[n] * fr;
    const float xr = th * 0.15915494309189535f;    // revolutions
    const float xf = xr - floorf(xr);
    const float sn = sin_rev(xf), cs = cos_rev(xf);
    float o0 = cs * y0 - sn * y1;
    float o1 = cs * y1 + sn * y0;
    unsigned short* dst;
    if (isq) {
        // log2(e) / sqrt(128): softmax runs in exp2 domain
        const float qs = 0.08838834764831845f * 1.4426950408889634f;
        o0 *= qs; o1 *= qs;
        dst = Qb + ((size_t)(b * H_ + hh) * T_ + t) * DH_;
    } else {
        dst = Kf + ((size_t)(b * KH_ + hh) * S_ + P_ + t) * DH_;
    }
    dst[lane]      = f2bf(o0);
    dst[lane + 64] = f2bf(o1);
}

// ---------------------------------------------------------------------------
// 3b) new-token V rows: sum the two qkv partials and transpose into
//     vT[b,kh,d,P+t] via 64x64 LDS tiles (coalesced both sides; replaces the
//     stride-8KB scalar stores that dominated norm_rope).
// ---------------------------------------------------------------------------
__global__ __launch_bounds__(256) void vnew_transpose(
    const unsigned short* __restrict__ qkv0, const unsigned short* __restrict__ qkv1,
    unsigned short* __restrict__ vT)
{
    __shared__ unsigned short tile[64][65];
    const int st = blockIdx.x;            // token-tile 0..7
    const int dt = blockIdx.y;            // d-tile 0..1
    const int bk = blockIdx.z;            // b*KH+kh 0..15
    const int b = bk >> 2, kh = bk & 3;
    const int tq = threadIdx.x & 15;      // d-quad
    const int ts = threadIdx.x >> 4;      // token row
    #pragma unroll
    for (int i = 0; i < 4; ++i) {
        const int si = ts + i * 16;
        const int n = b * T_ + st * 64 + si;
        const size_t off = (size_t)n * 3072 + 2560 + kh * 128 + dt * 64 + tq * 4;
        us4v a  = *(const us4v*)(qkv0 + off);
        us4v bb = *(const us4v*)(qkv1 + off);
        #pragma unroll
        for (int e = 0; e < 4; ++e)
            tile[si][tq * 4 + e] = f2bf(bf2f(a[e]) + bf2f(bb[e]));
    }
    __syncthreads();
    unsigned short* dst = vT + ((size_t)bk * DH_ + dt * 64) * S_ + P_ + st * 64;
    const int sq = threadIdx.x & 15;      // token-quad
    const int td = threadIdx.x >> 4;      // d row
    #pragma unroll
    for (int i = 0; i < 4; ++i) {
        const int di = td + i * 16;
        us4v o;
        o[0] = tile[sq*4+0][di]; o[1] = tile[sq*4+1][di];
        o[2] = tile[sq*4+2][di]; o[3] = tile[sq*4+3][di];
        *(us4v*)(dst + (size_t)di * S_ + sq * 4) = o;
    }
}

// ---------------------------------------------------------------------------
// 4) GQA flash attention, 3-way split-KV (stride-3 tile interleave),
//    XCD-aware block swizzle, 3-deep LDS ring with counted vmcnt + raw
//    s_barrier. exp2-domain online softmax, in-place exp, transient
//    shfl_xor P-exchange.  (r13/r16 body — measured best, 94.1-94.8 us)
// ---------------------------------------------------------------------------
__global__ __launch_bounds__(256, 3) void attn(
    const unsigned short* __restrict__ Qb, const unsigned short* __restrict__ Kf,
    const unsigned short* __restrict__ VT, unsigned short* __restrict__ op0,
    unsigned short* __restrict__ op1, unsigned short* __restrict__ op2,
    float2* __restrict__ ml)
{
    __shared__ short Ks[3][32 * 128];   // [s][d], 16B-chunk XOR(row&15) swizzle
    __shared__ short Vs[3][128 * 32];   // [d][s], 16B-chunk XOR((row>>1)&3) swizzle

    const int tid = threadIdx.x, lane = tid & 63, w = tid >> 6;
    // XCD-aware decode: 16 blocks sharing one (b,kvh) K/V panel land on one XCD
    const int c = blockIdx.x >> 8;                  // KV chunk 0..2
    const int y = blockIdx.x & 255;
    const int xcd = y & 7, slot = y >> 3;
    const int p = xcd + 8 * (slot >> 4);            // panel = b*KH + kvh, 0..15
    const int inner = slot & 15;
    const int b = p >> 2, kvh = p & 3;
    const int h = kvh * 4 + (inner >> 2);
    const int qt = inner & 3;
    const int t0 = qt * 128;

    const unsigned short* Qrow = Qb + (size_t)(b * H_ + h) * T_ * DH_;
    const unsigned short* Kb   = Kf + (size_t)(b * KH_ + kvh) * S_ * DH_;
    const unsigned short* VTb  = VT + (size_t)(b * KH_ + kvh) * DH_ * S_;

    const int ql = lane & 31;
    const int hi = lane >> 5;

    bf16x8 qf[8];
    {
        const unsigned short* qp = Qrow + (size_t)(t0 + w * 32 + ql) * DH_ + hi * 8;
        #pragma unroll
        for (int d0 = 0; d0 < 8; ++d0) qf[d0] = *(const bf16x8*)(qp + d0 * 16);
    }

    f32x16 o[4];
    #pragma unroll
    for (int d = 0; d < 4; ++d)
        #pragma unroll
        for (int r = 0; r < 16; ++r) o[d][r] = 0.f;
    float m_run = -INFINITY, l_run = 0.f;

    const int q_pos = P_ + t0 + w * 32 + ql;
    const int s_end_wave = P_ + t0 + w * 32 + 32;
    const int nt_full = (P_ + t0 + 128) >> 5;       // 116,120,124,128 for qt=0..3
    // chunk c handles tiles c, c+3, c+6, ... (stride-3 interleave, balanced)
    const int nj = (nt_full - c + 2) / 3;

    auto stage = [&](int buf, int tile) {
        const int s0 = tile << 5;
        #pragma unroll
        for (int cc = 0; cc < 2; ++cc) {
            const int cx = 2 * w + cc;
            const int krow = cx * 4 + (lane >> 4);
            const int kel  = 8 * ((lane & 15) ^ (krow & 15));
            GLDS16(Kb + (size_t)(s0 + krow) * DH_ + kel, &Ks[buf][cx * 512]);
            const int vrow = cx * 16 + (lane >> 2);
            const int vel  = 8 * ((lane & 3) ^ ((lane >> 3) & 3));  // (vrow>>1)&3
            GLDS16(VTb + (size_t)vrow * S_ + s0 + vel, &Vs[buf][cx * 512]);
        }
    };

    // prologue: 2 tiles in flight (4 GLDS per wave each)
    stage(0, c);
    if (nj > 1) stage(1, c + 3);

    for (int j = 0; j < nj; ++j) {
        // counted vmcnt: oldest 4 loads (= this tile) done; next tile's 4 stay in flight
        if (j + 1 < nj) asm volatile("s_waitcnt vmcnt(4)" ::: "memory");
        else            asm volatile("s_waitcnt vmcnt(0)" ::: "memory");
        __builtin_amdgcn_s_barrier();
        if (j + 2 < nj) stage((j + 2) % 3, c + 3 * (j + 2));

        const int t = c + 3 * j;
        const int s0 = t << 5;
        const int buf = j % 3;
        if (s0 < s_end_wave) {
            // ---- QK^T (swapped): st[r] = S^T[s=(r&3)+8*(r>>2)+4*hi][q=ql] (log2 domain)
            f32x16 st;
            #pragma unroll
            for (int r = 0; r < 16; ++r) st[r] = 0.f;
            {
                const char* kbase = (const char*)&Ks[buf][0] + ql * 256;
                const int sw = 16 * (ql & 15);
                #pragma unroll
                for (int d0 = 0; d0 < 8; ++d0) {
                    bf16x8 kfr = *(const bf16x8*)(kbase + ((d0 * 32 + 16 * hi) ^ sw));
                    st = __builtin_amdgcn_mfma_f32_32x32x16_bf16(kfr, qf[d0], st, 0, 0, 0);
                }
            }
            if (s0 + 31 > P_ + t0 + w * 32) {
                #pragma unroll
                for (int r = 0; r < 16; ++r) {
                    const int srow = (r & 3) + 8 * (r >> 2) + 4 * hi;
                    if (s0 + srow > q_pos) st[r] = -INFINITY;
                }
            }
            // ---- online softmax in exp2 domain, defer-max (THR = 8*log2e ~ 11.5)
            float m0_ = max3f(st[0], st[1], st[2]),  m1_ = max3f(st[3], st[4], st[5]);
            float m2_ = max3f(st[6], st[7], st[8]),  m3_ = max3f(st[9], st[10], st[11]);
            float m4_ = max3f(st[12], st[13], st[14]);
            float pmax = fmaxf(max3f(m0_, m1_, m2_), max3f(m3_, m4_, st[15]));
            pmax = fmaxf(pmax, __shfl_xor(pmax, 32));
            if (!__all(pmax <= m_run + 11.5f)) {
                const float m_new = fmaxf(m_run, pmax);
                const float alpha = ex2(m_run - m_new);
                l_run *= alpha;
                #pragma unroll
                for (int r = 0; r < 16; ++r) {
                    const int qr = (r & 3) + 8 * (r >> 2) + 4 * hi;
                    const float a = __shfl(alpha, qr);
                    #pragma unroll
                    for (int d = 0; d < 4; ++d) o[d][r] *= a;
                }
                m_run = m_new;
            }
            // ---- exp in place (st becomes P), running sum
            float psum = 0.f;
            #pragma unroll
            for (int r = 0; r < 16; ++r) { st[r] = ex2(st[r] - m_run); psum += st[r]; }
            psum += __shfl_xor(psum, 32);
            l_run += psum;
            // ---- P -> bf16 A-fragments (cvt_pk + transient partner exchange)
            unsigned pk[8];
            #pragma unroll
            for (int u = 0; u < 8; ++u) pk[u] = pkbf(st[2 * u], st[2 * u + 1]);
            union { bf16x8 v; unsigned u[4]; } pa0, pa1;
            { unsigned xx = (unsigned)__shfl_xor((int)pk[2], 32); pa0.u[0] = hi ? xx : pk[0]; }
            { unsigned xx = (unsigned)__shfl_xor((int)pk[3], 32); pa0.u[1] = hi ? xx : pk[1]; }
            { unsigned xx = (unsigned)__shfl_xor((int)pk[0], 32); pa0.u[2] = hi ? pk[2] : xx; }
            { unsigned xx = (unsigned)__shfl_xor((int)pk[1], 32); pa0.u[3] = hi ? pk[3] : xx; }
            { unsigned xx = (unsigned)__shfl_xor((int)pk[6], 32); pa1.u[0] = hi ? xx : pk[4]; }
            { unsigned xx = (unsigned)__shfl_xor((int)pk[7], 32); pa1.u[1] = hi ? xx : pk[5]; }
            { unsigned xx = (unsigned)__shfl_xor((int)pk[4], 32); pa1.u[2] = hi ? pk[6] : xx; }
            { unsigned xx = (unsigned)__shfl_xor((int)pk[5], 32); pa1.u[3] = hi ? pk[7] : xx; }
            // ---- PV: B-operand from vT LDS tile
            #pragma unroll
            for (int ch = 0; ch < 2; ++ch)
                #pragma unroll
                for (int db = 0; db < 4; ++db) {
                    const int vrow = db * 32 + ql;
                    bf16x8 vf = *(const bf16x8*)&Vs[buf][vrow * 32 + 8 * ((2 * ch + hi) ^ ((ql >> 1) & 3))];
                    o[db] = __builtin_amdgcn_mfma_f32_32x32x16_bf16(
                        ch ? pa1.v : pa0.v, vf, o[db], 0, 0, 0);
                }
        }
    }

    // ---- epilogue: write unnormalized partial O (bf16) + (m,l)
    unsigned short* op = (c == 0) ? op0 : (c == 1) ? op1 : op2;
    const int rowbase = (b * H_ + h) * T_ + t0 + w * 32;
    if (hi == 0) ml[c * NROWS + rowbase + ql] = float2{m_run, l_run};
    #pragma unroll
    for (int r = 0; r < 16; ++r) {
        const int qr = (r & 3) + 8 * (r >> 2) + 4 * hi;
        unsigned short* orow = op + (size_t)(rowbase + qr) * DH_;
        #pragma unroll
        for (int d = 0; d < 4; ++d)
            orow[d * 32 + ql] = f2bf(o[d][r]);
    }
}

// ---------------------------------------------------------------------------
// 5) combine partials: out = (sum_c 2^{m_c-m*} O_c) / (sum_c 2^{m_c-m*} l_c)
// ---------------------------------------------------------------------------
__global__ __launch_bounds__(256) void combine(
    const float2* __restrict__ ml,
    const unsigned short* __restrict__ op0, const unsigned short* __restrict__ op1,
    const unsigned short* __restrict__ op2, unsigned short* __restrict__ ao)
{
    const int row = blockIdx.x * 4 + (threadIdx.x >> 6);
    const int lane = threadIdx.x & 63;
    const float2 a0 = ml[row], a1 = ml[NROWS + row], a2 = ml[2 * NROWS + row];
    const float m = fmaxf(a0.x, fmaxf(a1.x, a2.x));
    const float w0 = ex2(a0.x - m), w1 = ex2(a1.x - m), w2 = ex2(a2.x - m);
    const float Linv = 1.0f / (w0 * a0.y + w1 * a1.y + w2 * a2.y);
    const size_t src = (size_t)row * DH_ + 2 * lane;
    const unsigned u0 = *(const unsigned*)(op0 + src);
    const unsigned u1 = *(const unsigned*)(op1 + src);
    const unsigned u2 = *(const unsigned*)(op2 + src);
    const float v0 = (bf2f((unsigned short)u0) * w0 + bf2f((unsigned short)u1) * w1 +
                      bf2f((unsigned short)u2) * w2) * Linv;
    const float v1 = (bf2f((unsigned short)(u0 >> 16)) * w0 + bf2f((unsigned short)(u1 >> 16)) * w1 +
                      bf2f((unsigned short)(u2 >> 16)) * w2) * Linv;
    // row = (b*H+h)*T + t  ->  ao[(b*T+t)][h*DH + d]
    const int t = row & 511, h = (row >> 9) & 15, b = row >> 13;
    unsigned short* dst = ao + ((size_t)(b * T_ + t) * (H_ * DH_)) + h * DH_ + 2 * lane;
    *(unsigned*)dst = pkbf(v0, v1);
}

// ---------------------------------------------------------------------------
// launch
// ---------------------------------------------------------------------------
extern "C" void kernel_launch(void* const* d_in, const int* in_sizes, int n_in,
                              void* d_out, int out_size, void* d_ws, size_t ws_size,
                              hipStream_t stream)
{
    const float* x   = (const float*)d_in[0];
    const float* kc  = (const float*)d_in[1];
    const float* vc  = (const float*)d_in[2];
    const float* wq  = (const float*)d_in[3];
    const float* wk  = (const float*)d_in[4];
    const float* wv  = (const float*)d_in[5];
    const float* wo  = (const float*)d_in[6];
    const float* qnw = (const float*)d_in[7];
    const float* knw = (const float*)d_in[8];
    const int*   pos = (const int*)d_in[9];
    float* out = (float*)d_out;

    char* ws = (char*)d_ws;
    // Live P1->P3:
    unsigned short* xb    = (unsigned short*)(ws + 0);          //  8 MB   x bf16
    unsigned short* wqkvb = (unsigned short*)(ws + 8388608);    // 12 MB   w_qkv bf16
    unsigned short* wob   = (unsigned short*)(ws + 20971520);   //  8 MB   w_o bf16 (P1-P6)
    unsigned short* qkvp0 = (unsigned short*)(ws + 29360128);   // 12.6 MB qkv partial 0
    unsigned short* qkvp1 = (unsigned short*)(ws + 41943040);   // 12.6 MB qkv partial 1 (contiguous)
    unsigned short* qb    = (unsigned short*)(ws + 54525952);   //  8 MB   Q bf16 (P3-P4)
    unsigned short* kfull = (unsigned short*)(ws + 62914560);   // 16 MB   K bf16 (P1-P4)
    unsigned short* vT    = (unsigned short*)(ws + 79691776);   // 16 MB   V bf16 (P1-P4)  -> ends 96468992
    // Overlays (regions dead by the time they're reused):
    unsigned short* op0   = (unsigned short*)(ws + 0);          //  8 MB  (xb region, P4-P5)
    unsigned short* op1   = (unsigned short*)(ws + 8388608);    //  8 MB  (wqkvb region, P4-P5)
    float2*         ml    = (float2*)(ws + 16777216);           //  1 MB  (wqkvb region, P4-P5)
    unsigned short* op2   = (unsigned short*)(ws + 29360128);   //  8 MB  (qkvp0 region, P4-P5)
    unsigned short* ao    = (unsigned short*)(ws + 37748736);   //  8 MB  (qkvp1 region, P5-P6)
    float*          po0   = (float*)(ws + 62914560);            // 16.8MB (kfull region, P6-P7)
    // po1 = po0 + M*N implicitly at ws+79691776 (vT region) — contiguous split-K partials

    hipLaunchKernelGGL(convert_all, dim3(2048 + 1792), dim3(256), 0, stream,
                       x, wq, wk, wv, wo, kc, vc, xb, wqkvb, wob, kfull, vT);
    hipLaunchKernelGGL(gemm_bt, dim3(2 * 16 * 24), dim3(256), 0, stream,
                       xb, wqkvb, (void*)qkvp0, 2048, 3072, 2048, 1, 2);
    hipLaunchKernelGGL(norm_rope, dim3(NTOK * 20 / 4), dim3(256), 0, stream,
                       qkvp0, qkvp1, qnw, knw, pos, qb, kfull);
    hipLaunchKernelGGL(vnew_transpose, dim3(T_ / 64, 2, B_ * KH_), dim3(256), 0, stream,
                       qkvp0, qkvp1, vT);
    hipLaunchKernelGGL(attn, dim3(NCHUNK * 256), dim3(256), 0, stream,
                       qb, kfull, vT, op0, op1, op2, ml);
    hipLaunchKernelGGL(combine, dim3(NROWS / 4), dim3(256), 0, stream,
                       ml, op0, op1, op2, ao);
    hipLaunchKernelGGL(gemm_bt, dim3(2 * 16 * 16), dim3(256), 0, stream,
                       ao, wob, (void*)po0, 2048, 2048, 2048, 0, 2);
    hipLaunchKernelGGL(reduce2, dim3(1024), dim3(256), 0, stream,
                       po0, po0 + (size_t)DM_ * NTOK, out);
}